// Round 4
// baseline (789.424 us; speedup 1.0000x reference)
//
#include <hip/hip_runtime.h>
#include <hip/hip_bf16.h>
#include <hip/hip_cooperative_groups.h>

namespace cg = cooperative_groups;

#define N_NODES 50000
#define N_EDGES 600000
#define D 128
#define H2 256
#define TN 16      // nodes per fused block (50000/16 = 3125 exactly)
#define MAXC 2048  // perm chunk capacity in LDS (aliases s_hidden: 16KB = 2048 int2)

#define BUILD_BLOCKS 256
#define BUILD_THREADS 1024
#define NCHUNK ((N_NODES + 1023) / 1024)   // 49 scan chunks

// ---------------------------------------------------------------------------
// One cooperative kernel: zero counts -> histogram -> 2-level exclusive scan
// -> scatter into dst-sorted perm2. 256 blocks x 1024 threads (co-resident).
__global__ __launch_bounds__(BUILD_THREADS) void build_kernel(
    const int* __restrict__ src, const int* __restrict__ dst,
    int* __restrict__ counts, int* __restrict__ offsets,
    int* __restrict__ cursor, int* __restrict__ blocksums,
    int2* __restrict__ perm2)
{
    cg::grid_group grid = cg::this_grid();
    __shared__ int wsum[16];
    const int tid = threadIdx.x;
    const int bid = blockIdx.x;
    const int gtid = bid * BUILD_THREADS + tid;
    const int gsize = BUILD_BLOCKS * BUILD_THREADS;  // 262144
    const int lane = tid & 63;
    const int wv = tid >> 6;

    // 0. zero counts
    for (int i = gtid; i < N_NODES; i += gsize) counts[i] = 0;
    grid.sync();

    // 1. histogram of dst
    for (int e = gtid; e < N_EDGES; e += gsize) atomicAdd(&counts[dst[e]], 1);
    grid.sync();

    // 2a. block-local exclusive scan: blocks 0..48 each scan 1024 counts
    int myscan = 0;
    if (bid < NCHUNK) {
        const int i = bid * 1024 + tid;
        const int myval = (i < N_NODES) ? counts[i] : 0;
        int x = myval;
        #pragma unroll
        for (int d = 1; d < 64; d <<= 1) {
            int t = __shfl_up(x, d, 64);
            if (lane >= d) x += t;
        }
        if (lane == 63) wsum[wv] = x;
        __syncthreads();
        if (tid == 0) {
            int s = 0;
            #pragma unroll
            for (int w = 0; w < 16; ++w) { s += wsum[w]; wsum[w] = s; }
        }
        __syncthreads();
        myscan = (wv > 0 ? wsum[wv - 1] : 0) + (x - myval);
        if (tid == 0) blocksums[bid] = wsum[15];
    }
    grid.sync();

    // 2b. block 0, one wave: exclusive scan of the 49 chunk sums -> bases
    if (bid == 0 && tid < 64) {
        const int v = (tid < NCHUNK) ? blocksums[tid] : 0;
        int x = v;
        #pragma unroll
        for (int d = 1; d < 64; d <<= 1) {
            int t = __shfl_up(x, d, 64);
            if (lane >= d) x += t;
        }
        if (tid < NCHUNK) blocksums[64 + tid] = x - v;  // exclusive base
    }
    grid.sync();

    // 2c. offsets = local scan + chunk base; prime cursor
    if (bid < NCHUNK) {
        const int i = bid * 1024 + tid;
        if (i < N_NODES) {
            const int v = myscan + blocksums[64 + bid];
            offsets[i] = v;
            cursor[i] = v;
        }
    }
    if (gtid == 0) offsets[N_NODES] = N_EDGES;
    grid.sync();

    // 3. scatter edges into dst-sorted order; pack local node id into bits 20..23
    for (int e = gtid; e < N_EDGES; e += gsize) {
        const int d = dst[e];
        const int p = atomicAdd(&cursor[d], 1);
        perm2[p] = make_int2(e | ((d & (TN - 1)) << 20), src[e]);
    }
}

// ---------------------------------------------------------------------------
// Fused gather + MLP + residual. Block = 16 nodes, 256 threads.
__global__ __launch_bounds__(256) void fused_kernel(
    const float* __restrict__ h, const float* __restrict__ ea,
    const int* __restrict__ offsets, const int2* __restrict__ perm2,
    const float* __restrict__ W1, const float* __restrict__ b1,
    const float* __restrict__ W2, const float* __restrict__ b2,
    const float* __restrict__ eps, float* __restrict__ out)
{
    __shared__ float s_aggr[TN][D];     // 8 KB
    __shared__ float s_hidden[TN][H2];  // 16 KB (phase A: aliased as perm staging)
    int2* s_perm = (int2*)&s_hidden[0][0];

    const int tid = threadIdx.x;
    const int node0 = blockIdx.x * TN;

    // zero s_aggr
    for (int i = tid; i < TN * D / 4; i += 256)
        ((float4*)s_aggr)[i] = make_float4(0.f, 0.f, 0.f, 0.f);

    const int beg = offsets[node0];
    const int end = offsets[node0 + TN];
    const int grp = tid >> 5;        // 0..7
    const int c = (tid & 31) << 2;   // float offset 0..124

    for (int cb = beg; cb < end; cb += MAXC) {
        const int cnt = min(end - cb, MAXC);
        __syncthreads();  // s_aggr zero done / prior s_perm use done
        for (int i = tid; i < cnt; i += 256) s_perm[i] = perm2[cb + i];
        __syncthreads();
        // contiguous sub-range per 32-lane group; batch 4 edges -> 8 loads
        // in flight; register accumulate, flush to LDS on dst change.
        const int per = (cnt + 7) >> 3;
        const int lo = grp * per;
        const int hi = min(lo + per, cnt);
        float4 acc = make_float4(0.f, 0.f, 0.f, 0.f);
        int tcur = -1;
        for (int j = lo; j < hi; j += 4) {
            const int nb = hi - j;  // >=1
            int2 p[4];
            #pragma unroll
            for (int u = 0; u < 4; ++u)
                p[u] = s_perm[min(j + u, hi - 1)];
            float4 ev[4], hv[4];
            #pragma unroll
            for (int u = 0; u < 4; ++u) {
                ev[u] = *(const float4*)(ea + (size_t)(p[u].x & 0xFFFFF) * D + c);
                hv[u] = *(const float4*)(h + (size_t)p[u].y * D + c);
            }
            #pragma unroll
            for (int u = 0; u < 4; ++u) {
                if (u < nb) {
                    const int t = p[u].x >> 20;
                    if (t != tcur) {
                        if (tcur >= 0) {
                            atomicAdd(&s_aggr[tcur][c + 0], acc.x);
                            atomicAdd(&s_aggr[tcur][c + 1], acc.y);
                            atomicAdd(&s_aggr[tcur][c + 2], acc.z);
                            atomicAdd(&s_aggr[tcur][c + 3], acc.w);
                        }
                        acc = make_float4(0.f, 0.f, 0.f, 0.f);
                        tcur = t;
                    }
                    acc.x += ev[u].x + hv[u].x;
                    acc.y += ev[u].y + hv[u].y;
                    acc.z += ev[u].z + hv[u].z;
                    acc.w += ev[u].w + hv[u].w;
                }
            }
        }
        if (tcur >= 0) {
            atomicAdd(&s_aggr[tcur][c + 0], acc.x);
            atomicAdd(&s_aggr[tcur][c + 1], acc.y);
            atomicAdd(&s_aggr[tcur][c + 2], acc.z);
            atomicAdd(&s_aggr[tcur][c + 3], acc.w);
        }
    }
    __syncthreads();

    // ---- GEMM1: hidden = relu(aggr @ W1 + b1) ----
    {
        const int j0 = (tid & 63) << 2;    // 0..252
        const int tbase = (tid >> 6) << 2; // 0,4,8,12
        float4 acc1[4];
        const float4 bv = *(const float4*)(b1 + j0);
        #pragma unroll
        for (int t = 0; t < 4; ++t) acc1[t] = bv;
        for (int k = 0; k < D; k += 4) {
            float4 w[4];
            #pragma unroll
            for (int q = 0; q < 4; ++q)
                w[q] = *(const float4*)(W1 + (size_t)(k + q) * H2 + j0);
            #pragma unroll
            for (int t = 0; t < 4; ++t) {
                const float4 a = *(const float4*)&s_aggr[tbase + t][k];
                acc1[t].x = fmaf(a.x, w[0].x, acc1[t].x);
                acc1[t].y = fmaf(a.x, w[0].y, acc1[t].y);
                acc1[t].z = fmaf(a.x, w[0].z, acc1[t].z);
                acc1[t].w = fmaf(a.x, w[0].w, acc1[t].w);
                acc1[t].x = fmaf(a.y, w[1].x, acc1[t].x);
                acc1[t].y = fmaf(a.y, w[1].y, acc1[t].y);
                acc1[t].z = fmaf(a.y, w[1].z, acc1[t].z);
                acc1[t].w = fmaf(a.y, w[1].w, acc1[t].w);
                acc1[t].x = fmaf(a.z, w[2].x, acc1[t].x);
                acc1[t].y = fmaf(a.z, w[2].y, acc1[t].y);
                acc1[t].z = fmaf(a.z, w[2].z, acc1[t].z);
                acc1[t].w = fmaf(a.z, w[2].w, acc1[t].w);
                acc1[t].x = fmaf(a.w, w[3].x, acc1[t].x);
                acc1[t].y = fmaf(a.w, w[3].y, acc1[t].y);
                acc1[t].z = fmaf(a.w, w[3].z, acc1[t].z);
                acc1[t].w = fmaf(a.w, w[3].w, acc1[t].w);
            }
        }
        __syncthreads();  // all reads of aliased s_perm done before hidden write
        #pragma unroll
        for (int t = 0; t < 4; ++t) {
            float4 r;
            r.x = fmaxf(acc1[t].x, 0.f);
            r.y = fmaxf(acc1[t].y, 0.f);
            r.z = fmaxf(acc1[t].z, 0.f);
            r.w = fmaxf(acc1[t].w, 0.f);
            *(float4*)&s_hidden[tbase + t][j0] = r;
        }
    }
    __syncthreads();

    // ---- GEMM2 + residual ----
    {
        const int i0 = (tid & 31) << 2;    // 0..124
        const int g = tid >> 5;            // 0..7 -> nodes g, g+8
        float4 acc2[2];
        const float4 bv = *(const float4*)(b2 + i0);
        acc2[0] = bv; acc2[1] = bv;
        for (int k = 0; k < H2; k += 4) {
            float4 w[4];
            #pragma unroll
            for (int q = 0; q < 4; ++q)
                w[q] = *(const float4*)(W2 + (size_t)(k + q) * D + i0);
            #pragma unroll
            for (int u = 0; u < 2; ++u) {
                const float4 a = *(const float4*)&s_hidden[g + u * 8][k];
                acc2[u].x = fmaf(a.x, w[0].x, acc2[u].x);
                acc2[u].y = fmaf(a.x, w[0].y, acc2[u].y);
                acc2[u].z = fmaf(a.x, w[0].z, acc2[u].z);
                acc2[u].w = fmaf(a.x, w[0].w, acc2[u].w);
                acc2[u].x = fmaf(a.y, w[1].x, acc2[u].x);
                acc2[u].y = fmaf(a.y, w[1].y, acc2[u].y);
                acc2[u].z = fmaf(a.y, w[1].z, acc2[u].z);
                acc2[u].w = fmaf(a.y, w[1].w, acc2[u].w);
                acc2[u].x = fmaf(a.z, w[2].x, acc2[u].x);
                acc2[u].y = fmaf(a.z, w[2].y, acc2[u].y);
                acc2[u].z = fmaf(a.z, w[2].z, acc2[u].z);
                acc2[u].w = fmaf(a.z, w[2].w, acc2[u].w);
                acc2[u].x = fmaf(a.w, w[3].x, acc2[u].x);
                acc2[u].y = fmaf(a.w, w[3].y, acc2[u].y);
                acc2[u].z = fmaf(a.w, w[3].z, acc2[u].z);
                acc2[u].w = fmaf(a.w, w[3].w, acc2[u].w);
            }
        }
        const float ep = 1.0f + eps[0];
        #pragma unroll
        for (int u = 0; u < 2; ++u) {
            const int node = node0 + g + u * 8;
            const float4 hv = *(const float4*)(h + (size_t)node * D + i0);
            float4 o;
            o.x = fmaf(ep, hv.x, acc2[u].x);
            o.y = fmaf(ep, hv.y, acc2[u].y);
            o.z = fmaf(ep, hv.z, acc2[u].z);
            o.w = fmaf(ep, hv.w, acc2[u].w);
            *(float4*)(out + (size_t)node * D + i0) = o;
        }
    }
}

extern "C" void kernel_launch(void* const* d_in, const int* in_sizes, int n_in,
                              void* d_out, int out_size, void* d_ws, size_t ws_size,
                              hipStream_t stream) {
    const float* h   = (const float*)d_in[0];
    const float* ea  = (const float*)d_in[1];
    const int*   src = (const int*)d_in[2];
    const int*   dst = (const int*)d_in[3];
    const float* W1  = (const float*)d_in[4];
    const float* b1  = (const float*)d_in[5];
    const float* W2  = (const float*)d_in[6];
    const float* b2  = (const float*)d_in[7];
    const float* eps = (const float*)d_in[8];
    float* out = (float*)d_out;

    char* ws = (char*)d_ws;
    int*  counts    = (int*)ws;                    // 200 KB
    int*  offsets   = (int*)(ws + 256 * 1024);     // 200 KB (+1)
    int*  cursor    = (int*)(ws + 512 * 1024);     // 200 KB
    int*  blocksums = (int*)(ws + 768 * 1024);     // 1 KB (64 sums + 64 bases)
    int2* perm2     = (int2*)(ws + 1024 * 1024);   // 4.8 MB

    void* args[] = { (void*)&src, (void*)&dst, (void*)&counts, (void*)&offsets,
                     (void*)&cursor, (void*)&blocksums, (void*)&perm2 };
    hipLaunchCooperativeKernel((void*)build_kernel, dim3(BUILD_BLOCKS),
                               dim3(BUILD_THREADS), args, 0, stream);

    fused_kernel<<<N_NODES / TN, 256, 0, stream>>>(
        h, ea, offsets, perm2, W1, b1, W2, b2, eps, out);
}